// Round 7
// baseline (92.178 us; speedup 1.0000x reference)
//
#include <hip/hip_runtime.h>

// CreateInstMap: out[r,c] = 1 + argmin_k sqrt((px-cx[k])^2 + (py-cy[k])^2)
//   px = (c+1) - reg[0,r,c], py = (r+1) - reg[1,r,c]; cy=cc[k,0], cx=cc[k,1].
//
// Round 7 = R6 + (a) DIAGNOSTIC double-launch: kernel is a pure function of
// its inputs, so launching it twice is semantically a no-op; dur_us becomes
// overhead + 2k, pinning the true kernel cost k (invisible to rocprof top-5
// since k < the 43us poison fills). (b) second-best tracking replaces the
// in-loop hazard check (13 -> 10 inner ops/px).
//
//  * Per-wave prune (8x32 strip): keep k iff d(k,anchor) <= dmin + 2R + 4,
//    R measured from the strip's pred points. Margin 4 >> fp error (~1e-2).
//    k-order compaction preserves first-index tie semantics. No barrier:
//    each wave owns cand[w].
//  * Main loop: BIT-EXACT reference d^2 (__fmul_rn/__fadd_rn on original
//    coords), strict '<', track best + second-best.
//  * Exactness: ref-mismatch needs earlier j with d2_j >= d2_min and
//    rn(sqrt) equal => d2_j <= d2_min(1+2^-21) => sec-best <= 2^-21*best.
//    End-check sec-best <= best*2^-19 (4x margin) -> fallback fires for
//    ~a handful of waves per image; fallback = bit-exact __fsqrt_rn pass.

#define H_ 1024
#define W_ 2048
#define K_ 64
#define HAZC 1.9073486e-6f   // 2^-19

typedef int ix4 __attribute__((ext_vector_type(4)));

__global__ __launch_bounds__(256) void inst_map_kernel(
    const float* __restrict__ reg,   // (2, H, W) float32
    const float* __restrict__ cc,    // (K, 2)    float32, [k] = (cy, cx)
    int* __restrict__ out)           // (H, W)    int32
{
    __shared__ float4 cand[4][K_ + 1];  // per wave: (cx, cy, kbits, 0) + pad

    const int tid  = threadIdx.x;
    const int w    = tid >> 6;               // wave id
    const int lane = tid & 63;
    const int tr0  = blockIdx.y * 32;
    const int tc0  = blockIdx.x * 32;
    const int r    = tr0 + w * 8 + (lane >> 3);   // wave strip: 8 rows x 32 cols
    const int c    = tc0 + ((lane & 7) << 2);     // 4 px/thread
    const int base = r * W_ + c;

    const float4 rx = *reinterpret_cast<const float4*>(reg + base);
    const float4 ry = *reinterpret_cast<const float4*>(reg + H_ * W_ + base);

    // exact reference pred values
    float px[4], py[4];
    const float yf = (float)(r + 1);
    px[0] = (float)(c + 1) - rx.x;  py[0] = yf - ry.x;
    px[1] = (float)(c + 2) - rx.y;  py[1] = yf - ry.y;
    px[2] = (float)(c + 3) - rx.z;  py[2] = yf - ry.z;
    px[3] = (float)(c + 4) - rx.w;  py[3] = yf - ry.w;

    // strip anchor (pixel coords 1-based); strip radius m = max |pred-a|^2
    const float ax = (float)tc0 + 16.5f;
    const float ay = (float)(tr0 + w * 8) + 4.5f;
    float m = 0.0f;
    #pragma unroll
    for (int i = 0; i < 4; ++i) {
        const float sx = px[i] - ax, sy = py[i] - ay;
        m = fmaxf(m, __fmaf_rn(sx, sx, sy * sy));
    }

    // per-lane center distance to anchor; merged max/min shuffle reduce
    const float cyk = cc[2 * lane];
    const float cxk = cc[2 * lane + 1];
    const float sxc = cxk - ax, syc = cyk - ay;
    const float d   = sqrtf(__fmaf_rn(sxc, sxc, syc * syc));
    float dmin = d;
    #pragma unroll
    for (int s = 1; s < 64; s <<= 1) {
        m    = fmaxf(m,    __shfl_xor(m, s, 64));
        dmin = fminf(dmin, __shfl_xor(dmin, s, 64));
    }

    // prune + k-order compaction into this wave's LDS region (no barrier)
    const bool keep = d <= dmin + 2.0f * sqrtf(m) + 4.0f;
    const unsigned long long mask = __ballot(keep);
    const int ncand = (int)__popcll(mask);
    if (keep) {
        const int pos = (int)__popcll(mask & ((1ull << lane) - 1ull));
        cand[w][pos] = make_float4(cxk, cyk, __int_as_float(lane + 1), 0.0f);
    }
    if (lane == 0)   // pad: +inf coords -> d2=+inf, never wins
        cand[w][ncand] = make_float4(INFINITY, INFINITY, __int_as_float(1), 0.0f);

    // ---- main loop: bit-exact reference d^2, best + second-best ----
    float best[4] = {INFINITY, INFINITY, INFINITY, INFINITY};
    float sec[4]  = {INFINITY, INFINITY, INFINITY, INFINITY};
    int   bidx[4] = {1, 1, 1, 1};

    float4 cd = cand[w][0];
    for (int j = 0; j < ncand; ++j) {
        const float4 nx = cand[w][j + 1];      // one-ahead prefetch (pad-safe)
        #pragma unroll
        for (int i = 0; i < 4; ++i) {
            const float dx = px[i] - cd.x;
            const float dy = py[i] - cd.y;
            const float d2 = __fadd_rn(__fmul_rn(dx, dx), __fmul_rn(dy, dy));
            const bool lt = d2 < best[i];
            const float mn = fminf(sec[i], d2);
            sec[i]  = lt ? best[i] : mn;
            best[i] = lt ? d2 : best[i];
            bidx[i] = lt ? __float_as_int(cd.z) : bidx[i];
        }
        cd = nx;
    }

    // sqrt-collision hazard end-check (see header proof)
    bool haz = false;
    #pragma unroll
    for (int i = 0; i < 4; ++i)
        haz = haz | (sec[i] - best[i] <= __fmul_rn(best[i], HAZC));

    // ---- fallback (~few waves per image): bit-exact sqrt compare ----
    if (__any(haz)) {
        float sb[4]  = {INFINITY, INFINITY, INFINITY, INFINITY};
        int   bi2[4] = {1, 1, 1, 1};
        for (int j = 0; j < ncand; ++j) {
            const float4 c2 = cand[w][j];
            const int kk = __float_as_int(c2.z);
            const float ecy = cc[2 * (kk - 1)];       // exact coords
            const float ecx = cc[2 * (kk - 1) + 1];
            #pragma unroll
            for (int i = 0; i < 4; ++i) {
                const float dx = px[i] - ecx;
                const float dy = py[i] - ecy;
                const float s2 = __fsqrt_rn(__fadd_rn(__fmul_rn(dx, dx),
                                                      __fmul_rn(dy, dy)));
                const bool lt = s2 < sb[i];           // strict: first-index ties
                sb[i]  = lt ? s2 : sb[i];
                bi2[i] = lt ? kk : bi2[i];
            }
        }
        #pragma unroll
        for (int i = 0; i < 4; ++i) bidx[i] = bi2[i];
    }

    const ix4 o = {bidx[0], bidx[1], bidx[2], bidx[3]};
    __builtin_nontemporal_store(o, reinterpret_cast<ix4*>(out + base));
}

extern "C" void kernel_launch(void* const* d_in, const int* in_sizes, int n_in,
                              void* d_out, int out_size, void* d_ws, size_t ws_size,
                              hipStream_t stream) {
    const float* reg = (const float*)d_in[0];   // instance_regressions (2,H,W)
    const float* cc  = (const float*)d_in[1];   // center_coords (K,2)
    int* out = (int*)d_out;                     // (H,W) int32

    dim3 grid(W_ / 32, H_ / 32);                // (64, 32) = 2048 blocks
    // DIAGNOSTIC double-launch: kernel is a pure function of d_in -> second
    // launch is semantically a no-op; dur_us = overhead + 2*k pins k.
    inst_map_kernel<<<grid, 256, 0, stream>>>(reg, cc, out);
    inst_map_kernel<<<grid, 256, 0, stream>>>(reg, cc, out);
}

// Round 8
// 83.746 us; speedup vs baseline: 1.1007x; 1.1007x over previous
//
#include <hip/hip_runtime.h>

// CreateInstMap: out[r,c] = 1 + argmin_k sqrt((px-cx[k])^2 + (py-cy[k])^2)
//   px = (c+1) - reg[0,r,c], py = (r+1) - reg[1,r,c]; cy=cc[k,0], cx=cc[k,1].
//
// Round 8. Cost model (validated via R7 double-launch: k≈13µs):
// inner loop issue dominates = ops/px * 4px * ~21cand * 2cy * 8waves/SIMD.
// So: g-form argmin (2 FMA/px) replaces bit-exact d^2 (5 ops/px):
//   g = ck - 2*sx'*cx' - 2*sy'*cy'  ( = d^2 - |p'|^2, per-px constant )
// in wave-anchor-shifted coords (|terms| <= ~7e6 -> fma abs err <= ~0.7).
//
// Exactness: reference mismatch requires an earlier-index j whose exact d2
// satisfies d2_j - d2_min <= 2^-21*d2 (rn-sqrt tie; ref keeps earlier idx).
// In g-units that gap is within +-2*(fma err 0.7) +- 2*(ref d2 rounding
// 0.75*ulp <= 0.75). End-check: sec - best <= fma(best+h, 2^-20, 4.0)
// (2x relative margin + 1.4x absolute margin), h = |p'|^2 per px. If any
// pixel trips, the wave re-runs the bit-exact reference chain
// (__fmul_rn/__fadd_rn/__fsqrt_rn, strict '<') over the pruned list
// (~23% of waves; candidates/exact coords reloaded).
//
// Per-wave prune (8x32 strip, no barrier, wave owns cand[w]): keep k iff
// d(k,anchor) <= dmin + 2R + 4, R = max strip |pred-anchor| (measured);
// margin 4 >> fp error (~1e-2). k-order compaction => first-index ties.

#define H_ 1024
#define W_ 2048
#define K_ 64
#define RELW 9.5367431640625e-7f   // 2^-20
#define ABSW 4.0f

typedef int ix4 __attribute__((ext_vector_type(4)));

__global__ __launch_bounds__(256) void inst_map_kernel(
    const float* __restrict__ reg,   // (2, H, W) float32
    const float* __restrict__ cc,    // (K, 2)    float32, [k] = (cy, cx)
    int* __restrict__ out)           // (H, W)    int32
{
    __shared__ float4 cand[4][K_ + 1];  // per wave: (sx, sy, ck, kbits) + pad

    const int tid  = threadIdx.x;
    const int w    = tid >> 6;               // wave id
    const int lane = tid & 63;
    const int tr0  = blockIdx.y * 32;
    const int tc0  = blockIdx.x * 32;
    const int r    = tr0 + w * 8 + (lane >> 3);   // wave strip: 8 rows x 32 cols
    const int c    = tc0 + ((lane & 7) << 2);     // 4 px/thread
    const int base = r * W_ + c;

    const float4 rx = *reinterpret_cast<const float4*>(reg + base);
    const float4 ry = *reinterpret_cast<const float4*>(reg + H_ * W_ + base);

    // strip anchor (pixel coords 1-based)
    const float ax = (float)tc0 + 16.5f;
    const float ay = (float)(tr0 + w * 8) + 4.5f;

    // shifted pred coords (single rounding: (c+1-ax) exact, one subtract),
    // g-coefficients, per-px h = |p'|^2 (doubles as radius accumulator)
    float pxn[4], pyn[4], h[4];
    {
        const float cshift = (float)c - ax;           // exact (int - int-.5)
        const float rshift = (float)(r + 1) - ay;     // exact
        const float rv[4] = {rx.x, rx.y, rx.z, rx.w};
        const float yv[4] = {ry.x, ry.y, ry.z, ry.w};
        #pragma unroll
        for (int i = 0; i < 4; ++i) {
            const float sx = (cshift + (float)(i + 1)) - rv[i]; // one rounding
            const float sy = rshift - yv[i];
            pxn[i] = -2.0f * sx;                      // exact scale
            pyn[i] = -2.0f * sy;
            h[i]   = __fmaf_rn(sx, sx, sy * sy);
        }
    }
    float m = fmaxf(fmaxf(h[0], h[1]), fmaxf(h[2], h[3]));

    // per-lane center, shifted; merged max/min shuffle reduce
    const float cyk = cc[2 * lane];
    const float cxk = cc[2 * lane + 1];
    const float sxc = cxk - ax, syc = cyk - ay;
    const float ck  = __fmaf_rn(sxc, sxc, syc * syc);
    const float d   = sqrtf(ck);
    float dmin = d;
    #pragma unroll
    for (int s = 1; s < 64; s <<= 1) {
        m    = fmaxf(m,    __shfl_xor(m, s, 64));
        dmin = fminf(dmin, __shfl_xor(dmin, s, 64));
    }

    // prune + k-order compaction into this wave's LDS region (no barrier)
    const bool keep = d <= dmin + 2.0f * sqrtf(m) + 4.0f;
    const unsigned long long mask = __ballot(keep);
    const int ncand = (int)__popcll(mask);
    if (keep) {
        const int pos = (int)__popcll(mask & ((1ull << lane) - 1ull));
        cand[w][pos] = make_float4(sxc, syc, ck, __int_as_float(lane + 1));
    }
    if (lane == 0)   // pad: ck=+inf -> g=+inf, never wins
        cand[w][ncand] = make_float4(0.0f, 0.0f, INFINITY, __int_as_float(1));

    // ---- main loop: 2 FMA per pixel-candidate, best + second-best ----
    float best[4] = {INFINITY, INFINITY, INFINITY, INFINITY};
    float sec[4]  = {INFINITY, INFINITY, INFINITY, INFINITY};
    int   bidx[4] = {1, 1, 1, 1};

    float4 cd = cand[w][0];
    for (int j = 0; j < ncand; ++j) {
        const float4 nx = cand[w][j + 1];      // one-ahead prefetch (pad-safe)
        #pragma unroll
        for (int i = 0; i < 4; ++i) {
            const float g = __fmaf_rn(pxn[i], cd.x,
                            __fmaf_rn(pyn[i], cd.y, cd.z));
            const bool lt = g < best[i];
            const float mn = fminf(sec[i], g);
            sec[i]  = lt ? best[i] : mn;
            best[i] = lt ? g : best[i];
            bidx[i] = lt ? __float_as_int(cd.w) : bidx[i];
        }
        cd = nx;
    }

    // hazard end-check: sec-best within the sqrt-collision + fp-error window
    bool haz = false;
    #pragma unroll
    for (int i = 0; i < 4; ++i)
        haz = haz | (sec[i] - best[i] <=
                     __fmaf_rn(best[i] + h[i], RELW, ABSW));

    // ---- fallback (~23% of waves): bit-exact reference sqrt compare ----
    if (__any(haz)) {
        // recompute exact reference pred values (reg reload is cache-hot)
        const float4 ex = *reinterpret_cast<const float4*>(reg + base);
        const float4 ey = *reinterpret_cast<const float4*>(reg + H_ * W_ + base);
        const float rv[4] = {ex.x, ex.y, ex.z, ex.w};
        const float yv[4] = {ey.x, ey.y, ey.z, ey.w};
        float px[4], py[4], sb[4];
        int bi2[4];
        const float yf = (float)(r + 1);
        #pragma unroll
        for (int i = 0; i < 4; ++i) {
            px[i] = (float)(c + i + 1) - rv[i];
            py[i] = yf - yv[i];
            sb[i] = INFINITY;
            bi2[i] = 1;
        }
        for (int j = 0; j < ncand; ++j) {
            const int kk = __float_as_int(cand[w][j].w);
            const float ecy = cc[2 * (kk - 1)];       // exact coords
            const float ecx = cc[2 * (kk - 1) + 1];
            #pragma unroll
            for (int i = 0; i < 4; ++i) {
                const float dx = px[i] - ecx;
                const float dy = py[i] - ecy;
                const float s2 = __fsqrt_rn(__fadd_rn(__fmul_rn(dx, dx),
                                                      __fmul_rn(dy, dy)));
                const bool lt = s2 < sb[i];           // strict: first-index ties
                sb[i]  = lt ? s2 : sb[i];
                bi2[i] = lt ? kk : bi2[i];
            }
        }
        #pragma unroll
        for (int i = 0; i < 4; ++i) bidx[i] = bi2[i];
    }

    const ix4 o = {bidx[0], bidx[1], bidx[2], bidx[3]};
    __builtin_nontemporal_store(o, reinterpret_cast<ix4*>(out + base));
}

extern "C" void kernel_launch(void* const* d_in, const int* in_sizes, int n_in,
                              void* d_out, int out_size, void* d_ws, size_t ws_size,
                              hipStream_t stream) {
    const float* reg = (const float*)d_in[0];   // instance_regressions (2,H,W)
    const float* cc  = (const float*)d_in[1];   // center_coords (K,2)
    int* out = (int*)d_out;                     // (H,W) int32

    dim3 grid(W_ / 32, H_ / 32);                // (64, 32) = 2048 blocks
    inst_map_kernel<<<grid, 256, 0, stream>>>(reg, cc, out);
}

// Round 9
// 82.994 us; speedup vs baseline: 1.1106x; 1.0091x over previous
//
#include <hip/hip_runtime.h>

// CreateInstMap: out[r,c] = 1 + argmin_k sqrt((px-cx[k])^2 + (py-cy[k])^2)
//   px = (c+1) - reg[0,r,c], py = (r+1) - reg[1,r,c]; cy=cc[k,0], cx=cc[k,1].
//
// Round 9: candidates move from LDS to the SCALAR domain. R2-R8 showed inner
// VALU count is not binding; the unpriced cost was the per-CU DS pipe
// (32 waves x 21 ds_read_b128 x 12cy ~ 4.3us/CU) + per-iter lgkm waits.
// Candidates are wave-uniform -> iterate the __ballot mask with scalar ctz
// (s_ff1) in ASCENDING k-order (preserves first-index ties) and fetch
// (sx', sy', ck) via v_readlane (uniform lane idx). Zero LDS, zero barrier,
// no compaction.
//
// Inner: g = ck - 2sx'cx' - 2sy'cy' (= d^2 - |p'|^2/px const), 6 VALU/px:
//   fma, fma, cmp, med3 (sec = median(g,best,sec) == lt?best:min(sec,g)),
//   min (best), cndmask (idx; kk is scalar).
// Exactness: ref-mismatch needs earlier-index j with exact d2_j - d2_min <=
// 2^-21*d2 (rn-sqrt tie). Anchor-shifted terms are <= ~2.5e5 (ulp ~0.03), so
// pair-gap distortion of g vs exact d2 is <= ~0.2 (fma roundings + shifted-
// coord rounding 2|s|*ulp(2048)). End-check window fma(best+h, 2^-20, 1.0)
// = 5x margin; ~2.5% of waves trip -> bit-exact __fsqrt_rn fallback pass.
// Prune (unchanged, margin 4.0 >> 1e-2 fp error): keep k iff
// d(k,anchor) <= dmin + 2R + 4, R = measured max strip |pred-anchor|.

#define H_ 1024
#define W_ 2048
#define K_ 64
#define RELW 9.5367431640625e-7f   // 2^-20
#define ABSW 1.0f

typedef int ix4 __attribute__((ext_vector_type(4)));

__device__ __forceinline__ float readlane_f(float v, int lane) {
    return __int_as_float(__builtin_amdgcn_readlane(__float_as_int(v), lane));
}

__global__ __launch_bounds__(256) void inst_map_kernel(
    const float* __restrict__ reg,   // (2, H, W) float32
    const float* __restrict__ cc,    // (K, 2)    float32, [k] = (cy, cx)
    int* __restrict__ out)           // (H, W)    int32
{
    const int tid  = threadIdx.x;
    const int w    = tid >> 6;               // wave id
    const int lane = tid & 63;
    const int tr0  = blockIdx.y * 32;
    const int tc0  = blockIdx.x * 32;
    const int r    = tr0 + w * 8 + (lane >> 3);   // wave strip: 8 rows x 32 cols
    const int c    = tc0 + ((lane & 7) << 2);     // 4 px/thread
    const int base = r * W_ + c;

    const float4 rx = *reinterpret_cast<const float4*>(reg + base);
    const float4 ry = *reinterpret_cast<const float4*>(reg + H_ * W_ + base);

    // strip anchor (pixel coords 1-based)
    const float ax = (float)tc0 + 16.5f;
    const float ay = (float)(tr0 + w * 8) + 4.5f;

    // shifted pred coords, g-coefficients, h = |p'|^2 (also radius accum)
    float pxn[4], pyn[4], h[4];
    {
        const float cshift = (float)c - ax;           // exact (int - half-int)
        const float rshift = (float)(r + 1) - ay;     // exact
        const float rv[4] = {rx.x, rx.y, rx.z, rx.w};
        const float yv[4] = {ry.x, ry.y, ry.z, ry.w};
        #pragma unroll
        for (int i = 0; i < 4; ++i) {
            const float sx = (cshift + (float)(i + 1)) - rv[i];
            const float sy = rshift - yv[i];
            pxn[i] = -2.0f * sx;                      // exact scale
            pyn[i] = -2.0f * sy;
            h[i]   = __fmaf_rn(sx, sx, sy * sy);
        }
    }
    float m = fmaxf(fmaxf(h[0], h[1]), fmaxf(h[2], h[3]));

    // per-lane center (lane == k), shifted; merged max/min shuffle reduce
    const float cyk = cc[2 * lane];
    const float cxk = cc[2 * lane + 1];
    const float sxc = cxk - ax, syc = cyk - ay;
    const float ck  = __fmaf_rn(sxc, sxc, syc * syc);
    const float d   = sqrtf(ck);
    float dmin = d;
    #pragma unroll
    for (int s = 1; s < 64; s <<= 1) {
        m    = fmaxf(m,    __shfl_xor(m, s, 64));
        dmin = fminf(dmin, __shfl_xor(dmin, s, 64));
    }

    // prune: wave-uniform candidate mask (no LDS, no compaction)
    const bool keep = d <= dmin + 2.0f * sqrtf(m) + 4.0f;
    const unsigned long long mask = __ballot(keep);

    // ---- main loop: scalar mask iteration + readlane broadcast ----
    float best[4] = {INFINITY, INFINITY, INFINITY, INFINITY};
    float sec[4]  = {INFINITY, INFINITY, INFINITY, INFINITY};
    int   bidx[4] = {1, 1, 1, 1};

    unsigned long long rem = mask;
    while (rem) {
        const int lj = (int)__builtin_ctzll(rem);   // lowest k first (tie order)
        rem &= rem - 1ull;
        const float cxj = readlane_f(sxc, lj);      // wave-uniform (SGPR)
        const float cyj = readlane_f(syc, lj);
        const float ckj = readlane_f(ck,  lj);
        const int   kk  = lj + 1;
        #pragma unroll
        for (int i = 0; i < 4; ++i) {
            const float g = __fmaf_rn(pxn[i], cxj,
                            __fmaf_rn(pyn[i], cyj, ckj));
            const bool lt = g < best[i];
            sec[i]  = __builtin_amdgcn_fmed3f(g, best[i], sec[i]);
            best[i] = fminf(best[i], g);
            bidx[i] = lt ? kk : bidx[i];
        }
    }

    // hazard end-check: sec-best within sqrt-collision + fp-distortion window
    bool haz = false;
    #pragma unroll
    for (int i = 0; i < 4; ++i)
        haz = haz | (sec[i] - best[i] <= __fmaf_rn(best[i] + h[i], RELW, ABSW));

    // ---- fallback (~2.5% of waves): bit-exact reference sqrt compare ----
    if (__any(haz)) {
        const float4 ex = *reinterpret_cast<const float4*>(reg + base);
        const float4 ey = *reinterpret_cast<const float4*>(reg + H_ * W_ + base);
        const float rv[4] = {ex.x, ex.y, ex.z, ex.w};
        const float yv[4] = {ey.x, ey.y, ey.z, ey.w};
        float px[4], py[4], sb[4];
        int bi2[4];
        const float yf = (float)(r + 1);
        #pragma unroll
        for (int i = 0; i < 4; ++i) {
            px[i] = (float)(c + i + 1) - rv[i];     // exact reference pred
            py[i] = yf - yv[i];
            sb[i] = INFINITY;
            bi2[i] = 1;
        }
        unsigned long long rem2 = mask;
        while (rem2) {
            const int lj = (int)__builtin_ctzll(rem2);
            rem2 &= rem2 - 1ull;
            const float ecy = cc[2 * lj];           // exact coords (s_load)
            const float ecx = cc[2 * lj + 1];
            #pragma unroll
            for (int i = 0; i < 4; ++i) {
                const float dx = px[i] - ecx;
                const float dy = py[i] - ecy;
                const float s2 = __fsqrt_rn(__fadd_rn(__fmul_rn(dx, dx),
                                                      __fmul_rn(dy, dy)));
                const bool lt = s2 < sb[i];         // strict: first-index ties
                sb[i]  = lt ? s2 : sb[i];
                bi2[i] = lt ? (lj + 1) : bi2[i];
            }
        }
        #pragma unroll
        for (int i = 0; i < 4; ++i) bidx[i] = bi2[i];
    }

    const ix4 o = {bidx[0], bidx[1], bidx[2], bidx[3]};
    __builtin_nontemporal_store(o, reinterpret_cast<ix4*>(out + base));
}

extern "C" void kernel_launch(void* const* d_in, const int* in_sizes, int n_in,
                              void* d_out, int out_size, void* d_ws, size_t ws_size,
                              hipStream_t stream) {
    const float* reg = (const float*)d_in[0];   // instance_regressions (2,H,W)
    const float* cc  = (const float*)d_in[1];   // center_coords (K,2)
    int* out = (int*)d_out;                     // (H,W) int32

    dim3 grid(W_ / 32, H_ / 32);                // (64, 32) = 2048 blocks
    inst_map_kernel<<<grid, 256, 0, stream>>>(reg, cc, out);
}